// Round 10
// baseline (378.979 us; speedup 1.0000x reference)
//
#include <hip/hip_runtime.h>
#include <hip/hip_fp16.h>
#include <cstddef>

#define TPB 256
#define EPA 8            // edges per thread in scatter
#define ACHUNK (EPA * TPB)
#define LSTR 136         // LDS h-tile row stride in halves (272 B: 2-way max)
#define CAPN 56          // padded slots per NODE (avg deg 16, max <44 w.h.p.)
#define GGRID 1024       // gemm12 grid (grid-stride over row-tiles)

typedef _Float16 f16x8 __attribute__((ext_vector_type(8)));
typedef float    f32x4 __attribute__((ext_vector_type(4)));

// ===========================================================================
// Direct per-node scatter: slot = atomicAdd(cnt[t]) (L2-resident, ~16/ctr);
// edat[t*CAPN+slot] = {(src<<8)|(flag<<7)|flag, bitcast(w)}  (w RAW —
// dinv_sel[tgt] is factored out of the row sum at gather time).
// Replaces the whole count/scan/bucket/csr chain (was 62 us at 10% occ).
// ===========================================================================
__global__ __launch_bounds__(256) void scatter_kernel(
        const int* __restrict__ tgt, const int* __restrict__ src,
        const float* __restrict__ ew, int* __restrict__ cnt,
        int2* __restrict__ edat, int E) {
    const int base = blockIdx.x * ACHUNK + threadIdx.x;
#pragma unroll
    for (int j = 0; j < EPA; ++j) {
        int e = base + j * TPB;
        if (e < E) {
            int t = tgt[e], s = src[e];
            float w = ew[e];
            int flag = (w < 0.0f) ? 1 : 0;
            int slot = atomicAdd(&cnt[t], 1);
            if (slot < CAPN)                    // overflow guard (never hit)
                edat[(size_t)t * CAPN + slot] =
                    make_int2((s << 8) | (flag << 7) | flag, __float_as_int(w));
        }
    }
}

// ===========================================================================
// fin_deg: node-parallel degrees + dinv (contiguous <=56-slot region read,
// full occupancy) + weight fp16 convert in the tail threads.
// ===========================================================================
__global__ __launch_bounds__(256) void fin_deg_kernel(
        const int* __restrict__ cnt, const int2* __restrict__ edat,
        float* __restrict__ dinvp, float* __restrict__ dinvn,
        const float* __restrict__ W1p, const float* __restrict__ W1n,
        const float* __restrict__ W2p, const float* __restrict__ W2n,
        __half* __restrict__ w16, int n) {
    int t = blockIdx.x * blockDim.x + threadIdx.x;
    if (t < n) {
        int c = cnt[t]; if (c > CAPN) c = CAPN;
        const int2* row = edat + (size_t)t * CAPN;
        float sp = 0.f, sn = 0.f;
        for (int i = 0; i < c; ++i) {
            int2 d = row[i];
            float w = __int_as_float(d.y);
            if (d.x & 1) sn -= w; else sp += w;   // neg: w<0 -> sn += |w|
        }
        dinvp[t] = rsqrtf(sp + 1.0f);
        dinvn[t] = rsqrtf(sn + 1.0f);
    } else {
        int q = t - n;
        if (q < 16384) {
            const float* Wsrc = (q < 4096) ? W1p : (q < 8192) ? W1n
                              : (q < 12288) ? W2p : W2n;
            float2 v = *(const float2*)(Wsrc + (size_t)(q & 4095) * 2);
            ((__half2*)w16)[q] = __floats2half2_rn(v.x, v.y);
        }
    }
}

// ===========================================================================
// convert_x: xs[row] = [x*dinvp | x*dinvn] (fp16, 256 B/row), 32 thr/row.
// ===========================================================================
__global__ __launch_bounds__(256) void convert_x_kernel(
        const float* __restrict__ x,
        const float* __restrict__ dinvp, const float* __restrict__ dinvn,
        __half* __restrict__ xs, int n) {
    int idx = blockIdx.x * blockDim.x + threadIdx.x;
    if (idx >= n * 32) return;
    int row = idx >> 5, jp = idx & 31;
    float2 v = *(const float2*)(x + (size_t)row * 64 + jp * 2);
    float dp = dinvp[row], dn = dinvn[row];
    __half2* xr = (__half2*)(xs + (size_t)row * 128);
    xr[jp]      = __floats2half2_rn(v.x * dp, v.y * dp);
    xr[jp + 32] = __floats2half2_rn(v.x * dn, v.y * dn);
}

// ===========================================================================
// gatherX: layer-1 aggregation.  edat.y = raw w; the row-constant factor
// dinv_sel[t] is applied ONCE after the sum:
//   accP = dp_t * (sum_pos w*xsP[src] + xsP[t])
//   accN = dn_t * (sum_neg w*xsN[src] - xsN[t])
// ===========================================================================
__global__ __launch_bounds__(256) void gatherX_kernel(
        const int* __restrict__ cnt, const int2* __restrict__ edat,
        const __half* __restrict__ xs,
        const float* __restrict__ dinvp, const float* __restrict__ dinvn,
        __half* __restrict__ agg, int n) {
    const int lane = threadIdx.x & 63;
    int t = (blockIdx.x * blockDim.x + threadIdx.x) >> 6;
    if (t >= n) return;
    t = __builtin_amdgcn_readfirstlane(t);
    const char* xB = (const char*)xs;
    int c = cnt[t]; if (c > CAPN) c = CAPN;
    const int beg = t * CAPN, end = beg + c;
    float aP[8], aN[8];
#pragma unroll
    for (int j = 0; j < 8; ++j) { aP[j] = 0.f; aN[j] = 0.f; }
    int e = beg;
    for (; e + 7 < end; e += 8) {
        unsigned long long dv[8];
#pragma unroll
        for (int j = 0; j < 8; ++j)
            dv[j] = __builtin_nontemporal_load(
                        (const unsigned long long*)(edat + e + j));
        const __half* r[8];
        float nvv[8];
        int fl[8];
#pragma unroll
        for (int j = 0; j < 8; ++j) {
            unsigned dx = (unsigned)dv[j];
            r[j]   = (const __half*)(xB + (dx & 0xFFFFFF80u));
            nvv[j] = __int_as_float((int)(dv[j] >> 32));
            fl[j]  = dx & 1;
        }
#pragma unroll
        for (int j = 0; j < 8; ++j) {
            float cc = __half2float(r[j][lane]) * nvv[j];
            if (fl[j]) aN[j] += cc; else aP[j] += cc;
        }
    }
    for (; e + 3 < end; e += 4) {
        unsigned long long dv[4];
#pragma unroll
        for (int j = 0; j < 4; ++j)
            dv[j] = __builtin_nontemporal_load(
                        (const unsigned long long*)(edat + e + j));
#pragma unroll
        for (int j = 0; j < 4; ++j) {
            unsigned dx = (unsigned)dv[j];
            const __half* r = (const __half*)(xB + (dx & 0xFFFFFF80u));
            float cc = __half2float(r[lane]) * __int_as_float((int)(dv[j] >> 32));
            if (dx & 1) aN[j] += cc; else aP[j] += cc;
        }
    }
    for (; e < end; ++e) {
        unsigned long long dv = __builtin_nontemporal_load(
                                    (const unsigned long long*)(edat + e));
        unsigned dx = (unsigned)dv;
        const __half* r = (const __half*)(xB + (dx & 0xFFFFFF80u));
        float cc = __half2float(r[lane]) * __int_as_float((int)(dv >> 32));
        if (dx & 1) aN[0] += cc; else aP[0] += cc;
    }
    float sumP = ((aP[0] + aP[1]) + (aP[2] + aP[3]))
               + ((aP[4] + aP[5]) + (aP[6] + aP[7]));
    float sumN = ((aN[0] + aN[1]) + (aN[2] + aN[3]))
               + ((aN[4] + aN[5]) + (aN[6] + aN[7]));
    float dp = dinvp[t], dn = dinvn[t];
    float accP = dp * (sumP + __half2float(xs[(size_t)t * 128 + lane]));
    float accN = dn * (sumN - __half2float(xs[(size_t)t * 128 + 64 + lane]));
    __builtin_nontemporal_store(__half_as_ushort((__half)accP),
        (unsigned short*)(agg + (size_t)t * 128 + lane));
    __builtin_nontemporal_store(__half_as_ushort((__half)accN),
        (unsigned short*)(agg + (size_t)t * 128 + 64 + lane));
}

// ===========================================================================
// gemm12: fused dual-layer GEMM, B-resident (round-9 verified structure).
// g2 ALIASES agg (row-local; agg reads precede g2 writes) — no __restrict__.
// ===========================================================================
__global__ __launch_bounds__(256, 2) void gemm12_mfma(
        const __half* agg,
        const __half* __restrict__ w1p, const __half* __restrict__ w1n,
        const float* __restrict__ b1p, const float* __restrict__ b1n,
        const __half* __restrict__ w2p, const __half* __restrict__ w2n,
        const float* __restrict__ dinvp, const float* __restrict__ dinvn,
        __half* g2, int n) {
    __shared__ _Float16 T[16 * LSTR];
    const int lane = threadIdx.x & 63;
    const int wv = threadIdx.x >> 6;
    const int m = lane & 15, quad = lane >> 4;
    const int t0 = 2 * wv, t1 = t0 + 1;      // this wave's two col-tiles
    const int ntile = (n + 15) >> 4;

    f16x8 B1a[4], B1b[4], B2a[4], B2b[4];
    const __half* W2 = (t0 < 4) ? w2p : w2n;
#pragma unroll
    for (int kc = 0; kc < 4; ++kc) {
        const __half* W1 = (kc < 2) ? w1p : w1n;
        const int ko = (kc & 1) * 32 + quad * 8;
        B1a[kc] = *(const f16x8*)(W1 + (size_t)(t0 * 16 + m) * 64 + ko);
        B1b[kc] = *(const f16x8*)(W1 + (size_t)(t1 * 16 + m) * 64 + ko);
        B2a[kc] = *(const f16x8*)(W2 + (size_t)((t0 & 3) * 16 + m) * 128 + kc * 32 + quad * 8);
        B2b[kc] = *(const f16x8*)(W2 + (size_t)((t1 & 3) * 16 + m) * 128 + kc * 32 + quad * 8);
    }
    const float bd0 = b1p[t0 * 16 + m] - b1n[t0 * 16 + m];
    const float bd1 = b1p[t1 * 16 + m] - b1n[t1 * 16 + m];

    int tile = blockIdx.x;
    f16x8 a1c[4];
    if (tile < ntile) {
        int arow = tile * 16 + m; if (arow > n - 1) arow = n - 1;
#pragma unroll
        for (int kc = 0; kc < 4; ++kc)
            a1c[kc] = *(const f16x8*)(agg + (size_t)arow * 128 + kc * 32 + quad * 8);
    }

    for (; tile < ntile; tile += gridDim.x) {
        const int row0 = tile * 16;
        f32x4 acc0 = (f32x4){0.f, 0.f, 0.f, 0.f};
        f32x4 acc1 = (f32x4){0.f, 0.f, 0.f, 0.f};
#pragma unroll
        for (int kc = 0; kc < 4; ++kc) {
            acc0 = __builtin_amdgcn_mfma_f32_16x16x32_f16(a1c[kc], B1a[kc], acc0, 0, 0, 0);
            acc1 = __builtin_amdgcn_mfma_f32_16x16x32_f16(a1c[kc], B1b[kc], acc1, 0, 0, 0);
        }
        float sp[4], sn[4]; int rows[4];
#pragma unroll
        for (int r = 0; r < 4; ++r) {
            int rw = row0 + quad * 4 + r;
            rows[r] = rw;
            sp[r] = (rw < n) ? dinvp[rw] : 0.f;
            sn[r] = (rw < n) ? dinvn[rw] : 0.f;
        }
#pragma unroll
        for (int r = 0; r < 4; ++r) {
            T[(quad * 4 + r) * LSTR + t0 * 16 + m] = (_Float16)fmaxf(acc0[r] + bd0, 0.f);
            T[(quad * 4 + r) * LSTR + t1 * 16 + m] = (_Float16)fmaxf(acc1[r] + bd1, 0.f);
        }
        const int ntile_i = tile + gridDim.x;
        f16x8 a1nx[4];
        if (ntile_i < ntile) {
            int arow = ntile_i * 16 + m; if (arow > n - 1) arow = n - 1;
#pragma unroll
            for (int kc = 0; kc < 4; ++kc)
                a1nx[kc] = *(const f16x8*)(agg + (size_t)arow * 128 + kc * 32 + quad * 8);
        }
        __syncthreads();
        f16x8 a2[4];
#pragma unroll
        for (int kc = 0; kc < 4; ++kc)
            a2[kc] = *(const f16x8*)(T + m * LSTR + kc * 32 + quad * 8);
        __syncthreads();
        f32x4 c0 = (f32x4){0.f, 0.f, 0.f, 0.f};
        f32x4 c1 = (f32x4){0.f, 0.f, 0.f, 0.f};
#pragma unroll
        for (int kc = 0; kc < 4; ++kc) {
            c0 = __builtin_amdgcn_mfma_f32_16x16x32_f16(a2[kc], B2a[kc], c0, 0, 0, 0);
            c1 = __builtin_amdgcn_mfma_f32_16x16x32_f16(a2[kc], B2b[kc], c1, 0, 0, 0);
        }
        const float* dsel0 = (t0 < 4) ? sp : sn;
#pragma unroll
        for (int r = 0; r < 4; ++r)
            if (rows[r] < n) {
                g2[(size_t)rows[r] * 128 + t0 * 16 + m] = (__half)(c0[r] * dsel0[r]);
                g2[(size_t)rows[r] * 128 + t1 * 16 + m] = (__half)(c1[r] * dsel0[r]);
            }
#pragma unroll
        for (int kc = 0; kc < 4; ++kc) a1c[kc] = a1nx[kc];
    }
}

// ===========================================================================
// gather64: layer-2 aggregation.  edat.y = raw w; pos/neg sums scaled once
// by dp_t/dn_t at the end.
// ===========================================================================
__global__ __launch_bounds__(256) void gather64_kernel(
        const int* __restrict__ cnt, const int2* __restrict__ edat,
        const __half* __restrict__ g2,
        const float* __restrict__ dinvp, const float* __restrict__ dinvn,
        const float* __restrict__ bp, const float* __restrict__ bn,
        float* __restrict__ out, int n) {
    const int lane = threadIdx.x & 63;
    int t = (blockIdx.x * blockDim.x + threadIdx.x) >> 6;
    if (t >= n) return;
    t = __builtin_amdgcn_readfirstlane(t);
    const char* gB = (const char*)g2;
    int c = cnt[t]; if (c > CAPN) c = CAPN;
    const int beg = t * CAPN, end = beg + c;
    float aP[8], aN[8];
#pragma unroll
    for (int j = 0; j < 8; ++j) { aP[j] = 0.f; aN[j] = 0.f; }
    int e = beg;
    for (; e + 7 < end; e += 8) {
        unsigned long long dv[8];
#pragma unroll
        for (int j = 0; j < 8; ++j)
            dv[j] = __builtin_nontemporal_load(
                        (const unsigned long long*)(edat + e + j));
#pragma unroll
        for (int j = 0; j < 8; ++j) {
            unsigned dx = (unsigned)dv[j];
            const __half* r = (const __half*)(gB + (dx & 0xFFFFFF80u));
            float cc = __half2float(r[lane]) * __int_as_float((int)(dv[j] >> 32));
            if (dx & 1) aN[j] += cc; else aP[j] += cc;
        }
    }
    for (; e + 3 < end; e += 4) {
        unsigned long long dv[4];
#pragma unroll
        for (int j = 0; j < 4; ++j)
            dv[j] = __builtin_nontemporal_load(
                        (const unsigned long long*)(edat + e + j));
#pragma unroll
        for (int j = 0; j < 4; ++j) {
            unsigned dx = (unsigned)dv[j];
            const __half* r = (const __half*)(gB + (dx & 0xFFFFFF80u));
            float cc = __half2float(r[lane]) * __int_as_float((int)(dv[j] >> 32));
            if (dx & 1) aN[j] += cc; else aP[j] += cc;
        }
    }
    for (; e < end; ++e) {
        unsigned long long dv = __builtin_nontemporal_load(
                                    (const unsigned long long*)(edat + e));
        unsigned dx = (unsigned)dv;
        const __half* r = (const __half*)(gB + (dx & 0xFFFFFF80u));
        float cc = __half2float(r[lane]) * __int_as_float((int)(dv >> 32));
        if (dx & 1) aN[0] += cc; else aP[0] += cc;
    }
    float sumP = ((aP[0] + aP[1]) + (aP[2] + aP[3]))
               + ((aP[4] + aP[5]) + (aP[6] + aP[7]));
    float sumN = ((aN[0] + aN[1]) + (aN[2] + aN[3]))
               + ((aN[4] + aN[5]) + (aN[6] + aN[7]));
    const float dp = dinvp[t], dn = dinvn[t];
    float hpv = __half2float(g2[(size_t)t * 128 + lane]);
    float hnv = __half2float(g2[(size_t)t * 128 + 64 + lane]);
    float o = dp * (sumP + hpv) + bp[lane] + dn * (sumN - hnv) - bn[lane];
    __builtin_nontemporal_store(fmaxf(o, 0.f), out + (size_t)t * 64 + lane);
}

// ---------------------------------------------------------------------------
extern "C" void kernel_launch(void* const* d_in, const int* in_sizes, int n_in,
                              void* d_out, int out_size, void* d_ws, size_t ws_size,
                              hipStream_t stream) {
    const float* x   = (const float*)d_in[0];
    const int*   ei  = (const int*)d_in[1];
    const float* ew  = (const float*)d_in[2];
    const float* W1p = (const float*)d_in[3];
    const float* b1p = (const float*)d_in[4];
    const float* W1n = (const float*)d_in[5];
    const float* b1n = (const float*)d_in[6];
    const float* W2p = (const float*)d_in[7];
    const float* b2p = (const float*)d_in[8];
    const float* W2n = (const float*)d_in[9];
    const float* b2n = (const float*)d_in[10];

    const int E = in_sizes[2];
    const int n = in_sizes[0] / 64;  // IN = 64
    const int* src = ei;
    const int* tgt = ei + E;

    // ws layout (4B units): cnt[n] | dinvp[n] | dinvn[n] | (pad) xs[64n] |
    //   w16[16384] | edat[2*CAPN*n] | agg[64n].  g2 aliases agg.  ~72 MB.
    int* wsi = (int*)d_ws;
    int* cnt = wsi;
    size_t o = (size_t)n;
    float* dinvp  = (float*)(wsi + o);  o += n;
    float* dinvn  = (float*)(wsi + o);  o += n;
    o = (o + 3) & ~(size_t)3;
    __half* xs  = (__half*)(wsi + o);   o += (size_t)n * 64;   // 128 halves/row
    __half* w16 = (__half*)(wsi + o);   o += 16384;
    __half* w1p16 = w16, *w1n16 = w16 + 8192, *w2p16 = w16 + 16384, *w2n16 = w16 + 24576;
    int2* edat = (int2*)(wsi + o);      o += 2 * (size_t)CAPN * n;
    __half* agg = (__half*)(wsi + o);   o += (size_t)n * 64;
    __half* g2  = agg;                  // aliased (row-local in gemm12)
    float*  out = (float*)d_out;

    hipMemsetAsync(cnt, 0, (size_t)n * sizeof(int), stream);

    const int gridA = (E + ACHUNK - 1) / ACHUNK;
    const int gridD = (n + 16384 + TPB - 1) / TPB;
    const int gridX = (n * 32 + TPB - 1) / TPB;
    const int gridW = (n * 64 + TPB - 1) / TPB;
    const int ntile = (n + 15) / 16;
    const int gridF = (ntile < GGRID) ? ntile : GGRID;

    scatter_kernel<<<gridA, TPB, 0, stream>>>(tgt, src, ew, cnt, edat, E);
    fin_deg_kernel<<<gridD, TPB, 0, stream>>>(cnt, edat, dinvp, dinvn,
                                              W1p, W1n, W2p, W2n, w16, n);
    convert_x_kernel<<<gridX, TPB, 0, stream>>>(x, dinvp, dinvn, xs, n);
    gatherX_kernel<<<gridW, TPB, 0, stream>>>(cnt, edat, xs, dinvp, dinvn, agg, n);
    gemm12_mfma<<<gridF, TPB, 0, stream>>>(agg, w1p16, w1n16, b1p, b1n,
                                           w2p16, w2n16, dinvp, dinvn, g2, n);
    gather64_kernel<<<gridW, TPB, 0, stream>>>(cnt, edat, g2, dinvp, dinvn,
                                               b2p, b2n, out, n);
}

// Round 11
// 299.744 us; speedup vs baseline: 1.2643x; 1.2643x over previous
//
#include <hip/hip_runtime.h>
#include <hip/hip_fp16.h>
#include <cstddef>

#define TPB 256
#define BSH 7            // log2(targets per bucket) — small buckets => 782 blocks, ~3/CU
#define BTGT 128         // targets per bucket
#define EPA 16           // edges per thread in scatter
#define ACHUNK (EPA * TPB)
#define LSTR 136         // LDS h-tile row stride in halves (272 B: 2-way max)
#define CAP 2560         // padded slots per bucket (mean 2048, +6 sigma ~ 2320)
#define NBMAX 1024       // compile-time bucket-count bound (n <= 131072)
#define GGRID 1024       // gemm12 grid (grid-stride over row-tiles)

typedef _Float16 f16x8 __attribute__((ext_vector_type(8)));
typedef float    f32x4 __attribute__((ext_vector_type(4)));

// ===========================================================================
// Bucket scatter into padded per-bucket regions (cursor-contiguous writes —
// round-10 lesson: random 8-B stores cost a full 64-B line writeback each).
// rec (int2) = {(t_local<<23)|(src<<6)|flag, bitcast(w)} at recs[b*CAP+slot].
// ===========================================================================
__global__ __launch_bounds__(256) void bucket_scatter_kernel(
        const int* __restrict__ tgt, const int* __restrict__ src,
        const float* __restrict__ ew, int* __restrict__ cnt_pad,
        int2* __restrict__ recs, int nb, int E) {
    __shared__ int lcnt[NBMAX];
    __shared__ int lbase[NBMAX];
    const int tid = threadIdx.x;
    for (int i = tid; i < nb; i += 256) lcnt[i] = 0;
    __syncthreads();
    const int base = blockIdx.x * ACHUNK + tid;
    int px[EPA], pw[EPA], mr[EPA], mb[EPA];
#pragma unroll
    for (int j = 0; j < EPA; ++j) {
        int e = base + j * TPB;
        if (e < E) {
            int t = tgt[e], s = src[e];
            float w = ew[e];
            int flag = (w < 0.0f) ? 1 : 0;
            mb[j] = t >> BSH;
            px[j] = ((t & (BTGT - 1)) << 23) | (s << 6) | flag;
            pw[j] = __float_as_int(w);
            mr[j] = atomicAdd(&lcnt[mb[j]], 1);
        }
    }
    __syncthreads();
    for (int i = tid; i < nb; i += 256)
        if (lcnt[i]) lbase[i] = atomicAdd(&cnt_pad[i * 16], lcnt[i]);
    __syncthreads();
#pragma unroll
    for (int j = 0; j < EPA; ++j) {
        int e = base + j * TPB;
        if (e < E) {
            int sl = lbase[mb[j]] + mr[j];
            if (sl < CAP)                       // overflow guard (never hit)
                recs[(size_t)mb[j] * CAP + sl] = make_int2(px[j], pw[j]);
        }
    }
}

// ===========================================================================
// Per-bucket CSR build + dinv + edat + x-convert (+ weight convert in b0).
// 256 threads, 128-target buckets, ~2048 edges/bucket (L1/L2-hot between
// the two sweeps).  nv = w * dinv_sel[tgt];
// edat[slot] = {(src<<8)|(flag<<7)|flag, bitcast(nv)}; rowse[t] = {beg,end}.
// ===========================================================================
__global__ __launch_bounds__(256) void csr_build_kernel(
        const int* __restrict__ cnt_pad, const int2* __restrict__ recs,
        int2* __restrict__ rowse, int2* __restrict__ edat,
        float* __restrict__ dinvp, float* __restrict__ dinvn,
        const float* __restrict__ x,
        const float* __restrict__ W1p, const float* __restrict__ W1n,
        const float* __restrict__ W2p, const float* __restrict__ W2n,
        __half* __restrict__ xs, __half* __restrict__ w16, int n) {
    __shared__ int   hcnt[BTGT];
    __shared__ int   cur[BTGT];
    __shared__ int   sm[BTGT];
    __shared__ float sdp[BTGT];
    __shared__ float sdn[BTGT];
    const int b = blockIdx.x, tid = threadIdx.x;
    int cnt = cnt_pad[b * 16]; if (cnt > CAP) cnt = CAP;
    const int beg = b * CAP, end = beg + cnt;
    if (tid < BTGT) {
        hcnt[tid] = 0;
        sdp[tid] = 0.f;
        sdn[tid] = 0.f;
    }
    __syncthreads();
    for (int i = beg + tid; i < end; i += 256) {
        int2 r = recs[i];
        int tl = ((unsigned)r.x) >> 23;
        atomicAdd(&hcnt[tl], 1);
        float w = __int_as_float(r.y);
        if (w > 0.0f)      atomicAdd(&sdp[tl], w);
        else if (w < 0.0f) atomicAdd(&sdn[tl], -w);
    }
    __syncthreads();
    int own = 0;
    if (tid < BTGT) {
        own = hcnt[tid];
        sm[tid] = own;
    }
    __syncthreads();
#pragma unroll
    for (int off = 1; off < BTGT; off <<= 1) {
        int add = (tid < BTGT && tid >= off) ? sm[tid - off] : 0;
        __syncthreads();
        if (tid < BTGT) sm[tid] += add;
        __syncthreads();
    }
    const int t0 = b << BSH;
    if (tid < BTGT) {
        int excl = sm[tid] - own;
        cur[tid] = beg + excl;
        const int t = t0 + tid;
        if (t < n) {
            rowse[t] = make_int2(beg + excl, beg + excl + own);
            float dp = rsqrtf(sdp[tid] + 1.0f);
            float dn = rsqrtf(sdn[tid] + 1.0f);
            dinvp[t] = dp; dinvn[t] = dn;
            sdp[tid] = dp; sdn[tid] = dn;      // reuse as dinv
        }
    }
    __syncthreads();
    for (int i = beg + tid; i < end; i += 256) {
        int2 r = recs[i];
        int tl = ((unsigned)r.x) >> 23;
        int slot = atomicAdd(&cur[tl], 1);
        float w = __int_as_float(r.y);
        int flag = r.x & 1;
        float nv = w * (flag ? sdn[tl] : sdp[tl]);
        int srcflag = (((r.x >> 6) & 0x1FFFF) << 8) | (flag << 7) | flag;
        edat[slot] = make_int2(srcflag, __float_as_int(nv));
    }
    // ---- convert this bucket's x rows: xs[t] = [x*dp | x*dn] (fp16) ----
    for (int it = tid; it < (BTGT << 5); it += 256) {
        int j = it >> 5, jp = it & 31;
        int tt = t0 + j;
        if (tt >= n) continue;
        float2 v = *(const float2*)(x + (size_t)tt * 64 + jp * 2);
        float dp = sdp[j], dn = sdn[j];
        __half2* xr = (__half2*)(xs + (size_t)tt * 128);
        xr[jp]      = __floats2half2_rn(v.x * dp, v.y * dp);
        xr[jp + 32] = __floats2half2_rn(v.x * dn, v.y * dn);
    }
    // ---- block 0: convert the 4 weight matrices ----
    if (b == 0) {
        for (int q = tid; q < 16384; q += 256) {
            const float* Wsrc = (q < 4096) ? W1p : (q < 8192) ? W1n
                              : (q < 12288) ? W2p : W2n;
            float2 v = *(const float2*)(Wsrc + (size_t)(q & 4095) * 2);
            ((__half2*)w16)[q] = __floats2half2_rn(v.x, v.y);
        }
    }
}

// ===========================================================================
// gatherX: layer-1 aggregation (1 row per wave, unroll 8, nt streams).
// ===========================================================================
__global__ __launch_bounds__(256) void gatherX_kernel(
        const int2* __restrict__ rowse, const int2* __restrict__ edat,
        const __half* __restrict__ xs,
        const float* __restrict__ dinvp, const float* __restrict__ dinvn,
        __half* __restrict__ agg, int n) {
    const int lane = threadIdx.x & 63;
    int t = (blockIdx.x * blockDim.x + threadIdx.x) >> 6;
    if (t >= n) return;
    t = __builtin_amdgcn_readfirstlane(t);
    const char* xB = (const char*)xs;
    int2 se = rowse[t];
    int beg = se.x, end = se.y;
    float aP[8], aN[8];
#pragma unroll
    for (int j = 0; j < 8; ++j) { aP[j] = 0.f; aN[j] = 0.f; }
    int e = beg;
    for (; e + 7 < end; e += 8) {
        unsigned long long dv[8];
#pragma unroll
        for (int j = 0; j < 8; ++j)
            dv[j] = __builtin_nontemporal_load(
                        (const unsigned long long*)(edat + e + j));
        const __half* r[8];
        float nvv[8];
        int fl[8];
#pragma unroll
        for (int j = 0; j < 8; ++j) {
            unsigned dx = (unsigned)dv[j];
            r[j]   = (const __half*)(xB + (dx & 0xFFFFFF80u));
            nvv[j] = __int_as_float((int)(dv[j] >> 32));
            fl[j]  = dx & 1;
        }
#pragma unroll
        for (int j = 0; j < 8; ++j) {
            float c = __half2float(r[j][lane]) * nvv[j];
            if (fl[j]) aN[j] += c; else aP[j] += c;
        }
    }
    for (; e + 3 < end; e += 4) {
        unsigned long long dv[4];
#pragma unroll
        for (int j = 0; j < 4; ++j)
            dv[j] = __builtin_nontemporal_load(
                        (const unsigned long long*)(edat + e + j));
#pragma unroll
        for (int j = 0; j < 4; ++j) {
            unsigned dx = (unsigned)dv[j];
            const __half* r = (const __half*)(xB + (dx & 0xFFFFFF80u));
            float c = __half2float(r[lane]) * __int_as_float((int)(dv[j] >> 32));
            if (dx & 1) aN[j] += c; else aP[j] += c;
        }
    }
    for (; e < end; ++e) {
        unsigned long long dv = __builtin_nontemporal_load(
                                    (const unsigned long long*)(edat + e));
        unsigned dx = (unsigned)dv;
        const __half* r = (const __half*)(xB + (dx & 0xFFFFFF80u));
        float c = __half2float(r[lane]) * __int_as_float((int)(dv >> 32));
        if (dx & 1) aN[0] += c; else aP[0] += c;
    }
    float accP = ((aP[0] + aP[1]) + (aP[2] + aP[3]))
               + ((aP[4] + aP[5]) + (aP[6] + aP[7]));
    float accN = ((aN[0] + aN[1]) + (aN[2] + aN[3]))
               + ((aN[4] + aN[5]) + (aN[6] + aN[7]));
    float sp = dinvp[t], sn = dinvn[t];
    accP += sp * __half2float(xs[(size_t)t * 128 + lane]);
    accN -= sn * __half2float(xs[(size_t)t * 128 + 64 + lane]);
    __builtin_nontemporal_store(__half_as_ushort((__half)accP),
        (unsigned short*)(agg + (size_t)t * 128 + lane));
    __builtin_nontemporal_store(__half_as_ushort((__half)accN),
        (unsigned short*)(agg + (size_t)t * 128 + 64 + lane));
}

// ===========================================================================
// gemm12: fused dual-layer GEMM, B-resident (round-9 verified structure).
// g2 ALIASES agg (row-local; agg reads precede g2 writes) — no __restrict__.
// ===========================================================================
__global__ __launch_bounds__(256, 2) void gemm12_mfma(
        const __half* agg,
        const __half* __restrict__ w1p, const __half* __restrict__ w1n,
        const float* __restrict__ b1p, const float* __restrict__ b1n,
        const __half* __restrict__ w2p, const __half* __restrict__ w2n,
        const float* __restrict__ dinvp, const float* __restrict__ dinvn,
        __half* g2, int n) {
    __shared__ _Float16 T[16 * LSTR];
    const int lane = threadIdx.x & 63;
    const int wv = threadIdx.x >> 6;
    const int m = lane & 15, quad = lane >> 4;
    const int t0 = 2 * wv, t1 = t0 + 1;      // this wave's two col-tiles
    const int ntile = (n + 15) >> 4;

    f16x8 B1a[4], B1b[4], B2a[4], B2b[4];
    const __half* W2 = (t0 < 4) ? w2p : w2n;
#pragma unroll
    for (int kc = 0; kc < 4; ++kc) {
        const __half* W1 = (kc < 2) ? w1p : w1n;
        const int ko = (kc & 1) * 32 + quad * 8;
        B1a[kc] = *(const f16x8*)(W1 + (size_t)(t0 * 16 + m) * 64 + ko);
        B1b[kc] = *(const f16x8*)(W1 + (size_t)(t1 * 16 + m) * 64 + ko);
        B2a[kc] = *(const f16x8*)(W2 + (size_t)((t0 & 3) * 16 + m) * 128 + kc * 32 + quad * 8);
        B2b[kc] = *(const f16x8*)(W2 + (size_t)((t1 & 3) * 16 + m) * 128 + kc * 32 + quad * 8);
    }
    const float bd0 = b1p[t0 * 16 + m] - b1n[t0 * 16 + m];
    const float bd1 = b1p[t1 * 16 + m] - b1n[t1 * 16 + m];

    int tile = blockIdx.x;
    f16x8 a1c[4];
    if (tile < ntile) {
        int arow = tile * 16 + m; if (arow > n - 1) arow = n - 1;
#pragma unroll
        for (int kc = 0; kc < 4; ++kc)
            a1c[kc] = *(const f16x8*)(agg + (size_t)arow * 128 + kc * 32 + quad * 8);
    }

    for (; tile < ntile; tile += gridDim.x) {
        const int row0 = tile * 16;
        f32x4 acc0 = (f32x4){0.f, 0.f, 0.f, 0.f};
        f32x4 acc1 = (f32x4){0.f, 0.f, 0.f, 0.f};
#pragma unroll
        for (int kc = 0; kc < 4; ++kc) {
            acc0 = __builtin_amdgcn_mfma_f32_16x16x32_f16(a1c[kc], B1a[kc], acc0, 0, 0, 0);
            acc1 = __builtin_amdgcn_mfma_f32_16x16x32_f16(a1c[kc], B1b[kc], acc1, 0, 0, 0);
        }
        float sp[4], sn[4]; int rows[4];
#pragma unroll
        for (int r = 0; r < 4; ++r) {
            int rw = row0 + quad * 4 + r;
            rows[r] = rw;
            sp[r] = (rw < n) ? dinvp[rw] : 0.f;
            sn[r] = (rw < n) ? dinvn[rw] : 0.f;
        }
#pragma unroll
        for (int r = 0; r < 4; ++r) {
            T[(quad * 4 + r) * LSTR + t0 * 16 + m] = (_Float16)fmaxf(acc0[r] + bd0, 0.f);
            T[(quad * 4 + r) * LSTR + t1 * 16 + m] = (_Float16)fmaxf(acc1[r] + bd1, 0.f);
        }
        const int ntile_i = tile + gridDim.x;
        f16x8 a1nx[4];
        if (ntile_i < ntile) {
            int arow = ntile_i * 16 + m; if (arow > n - 1) arow = n - 1;
#pragma unroll
            for (int kc = 0; kc < 4; ++kc)
                a1nx[kc] = *(const f16x8*)(agg + (size_t)arow * 128 + kc * 32 + quad * 8);
        }
        __syncthreads();
        f16x8 a2[4];
#pragma unroll
        for (int kc = 0; kc < 4; ++kc)
            a2[kc] = *(const f16x8*)(T + m * LSTR + kc * 32 + quad * 8);
        __syncthreads();
        f32x4 c0 = (f32x4){0.f, 0.f, 0.f, 0.f};
        f32x4 c1 = (f32x4){0.f, 0.f, 0.f, 0.f};
#pragma unroll
        for (int kc = 0; kc < 4; ++kc) {
            c0 = __builtin_amdgcn_mfma_f32_16x16x32_f16(a2[kc], B2a[kc], c0, 0, 0, 0);
            c1 = __builtin_amdgcn_mfma_f32_16x16x32_f16(a2[kc], B2b[kc], c1, 0, 0, 0);
        }
        const float* dsel0 = (t0 < 4) ? sp : sn;
#pragma unroll
        for (int r = 0; r < 4; ++r)
            if (rows[r] < n) {
                g2[(size_t)rows[r] * 128 + t0 * 16 + m] = (__half)(c0[r] * dsel0[r]);
                g2[(size_t)rows[r] * 128 + t1 * 16 + m] = (__half)(c1[r] * dsel0[r]);
            }
#pragma unroll
        for (int kc = 0; kc < 4; ++kc) a1c[kc] = a1nx[kc];
    }
}

// ===========================================================================
// gather64: layer-2 aggregation.
// ===========================================================================
__global__ __launch_bounds__(256) void gather64_kernel(
        const int2* __restrict__ rowse, const int2* __restrict__ edat,
        const __half* __restrict__ g2,
        const float* __restrict__ dinvp, const float* __restrict__ dinvn,
        const float* __restrict__ bp, const float* __restrict__ bn,
        float* __restrict__ out, int n) {
    const int lane = threadIdx.x & 63;
    int t = (blockIdx.x * blockDim.x + threadIdx.x) >> 6;
    if (t >= n) return;
    t = __builtin_amdgcn_readfirstlane(t);
    const char* gB = (const char*)g2;
    int2 se = rowse[t];
    int beg = se.x, end = se.y;
    float ac[8];
#pragma unroll
    for (int j = 0; j < 8; ++j) ac[j] = 0.f;
    int e = beg;
    for (; e + 7 < end; e += 8) {
        unsigned long long dv[8];
#pragma unroll
        for (int j = 0; j < 8; ++j)
            dv[j] = __builtin_nontemporal_load(
                        (const unsigned long long*)(edat + e + j));
#pragma unroll
        for (int j = 0; j < 8; ++j) {
            unsigned dx = (unsigned)dv[j];
            const __half* r = (const __half*)(gB + (dx & 0xFFFFFF80u));
            ac[j] += __half2float(r[lane]) * __int_as_float((int)(dv[j] >> 32));
        }
    }
    for (; e + 3 < end; e += 4) {
        unsigned long long dv[4];
#pragma unroll
        for (int j = 0; j < 4; ++j)
            dv[j] = __builtin_nontemporal_load(
                        (const unsigned long long*)(edat + e + j));
#pragma unroll
        for (int j = 0; j < 4; ++j) {
            unsigned dx = (unsigned)dv[j];
            const __half* r = (const __half*)(gB + (dx & 0xFFFFFF80u));
            ac[j] += __half2float(r[lane]) * __int_as_float((int)(dv[j] >> 32));
        }
    }
    for (; e < end; ++e) {
        unsigned long long dv = __builtin_nontemporal_load(
                                    (const unsigned long long*)(edat + e));
        unsigned dx = (unsigned)dv;
        const __half* r = (const __half*)(gB + (dx & 0xFFFFFF80u));
        ac[0] += __half2float(r[lane]) * __int_as_float((int)(dv >> 32));
    }
    float acc = ((ac[0] + ac[1]) + (ac[2] + ac[3]))
              + ((ac[4] + ac[5]) + (ac[6] + ac[7]));
    const float dp = dinvp[t], dn = dinvn[t];
    float hpv = __half2float(g2[(size_t)t * 128 + lane]);
    float hnv = __half2float(g2[(size_t)t * 128 + 64 + lane]);
    float o = acc + hpv * dp + bp[lane] - hnv * dn - bn[lane];
    __builtin_nontemporal_store(fmaxf(o, 0.f), out + (size_t)t * 64 + lane);
}

// ---------------------------------------------------------------------------
extern "C" void kernel_launch(void* const* d_in, const int* in_sizes, int n_in,
                              void* d_out, int out_size, void* d_ws, size_t ws_size,
                              hipStream_t stream) {
    const float* x   = (const float*)d_in[0];
    const int*   ei  = (const int*)d_in[1];
    const float* ew  = (const float*)d_in[2];
    const float* W1p = (const float*)d_in[3];
    const float* b1p = (const float*)d_in[4];
    const float* W1n = (const float*)d_in[5];
    const float* b1n = (const float*)d_in[6];
    const float* W2p = (const float*)d_in[7];
    const float* b2p = (const float*)d_in[8];
    const float* W2n = (const float*)d_in[9];
    const float* b2n = (const float*)d_in[10];

    const int E = in_sizes[2];
    const int n = in_sizes[0] / 64;  // IN = 64
    const int nb = (n + BTGT - 1) >> BSH;     // 782 buckets
    const int* src = ei;
    const int* tgt = ei + E;

    // ws layout (4B units): cnt_pad[nb*16] | rowse[2n] | dinvp[n] | dinvn[n] |
    //   xs[64n] | w16[16384] | recs[2*nb*CAP] | edat[2*nb*CAP] | agg[64n].
    //   g2 aliases agg.  ~76 MB.
    int* wsi     = (int*)d_ws;
    int* cnt_pad = wsi;
    size_t o = (size_t)nb * 16;
    o = (o + 3) & ~(size_t)3;
    int2*  rowse  = (int2*)(wsi + o);   o += 2 * (size_t)n;
    float* dinvp  = (float*)(wsi + o);  o += n;
    float* dinvn  = (float*)(wsi + o);  o += n;
    o = (o + 3) & ~(size_t)3;
    __half* xs  = (__half*)(wsi + o);   o += (size_t)n * 64;   // 128 halves/row
    __half* w16 = (__half*)(wsi + o);   o += 16384;
    __half* w1p16 = w16, *w1n16 = w16 + 8192, *w2p16 = w16 + 16384, *w2n16 = w16 + 24576;
    int2* recs = (int2*)(wsi + o);      o += 2 * (size_t)nb * CAP;
    int2* edat = (int2*)(wsi + o);      o += 2 * (size_t)nb * CAP;
    __half* agg = (__half*)(wsi + o);   o += (size_t)n * 64;
    __half* g2  = agg;                  // aliased (row-local in gemm12)
    float*  out = (float*)d_out;

    hipMemsetAsync(cnt_pad, 0, (size_t)nb * 16 * sizeof(int), stream);

    const int gridA = (E + ACHUNK - 1) / ACHUNK;
    const int gridW = (n * 64 + TPB - 1) / TPB;
    const int ntile = (n + 15) / 16;
    const int gridF = (ntile < GGRID) ? ntile : GGRID;

    bucket_scatter_kernel<<<gridA, TPB, 0, stream>>>(tgt, src, ew, cnt_pad, recs, nb, E);
    csr_build_kernel<<<nb, TPB, 0, stream>>>(cnt_pad, recs, rowse, edat,
                                             dinvp, dinvn, x,
                                             W1p, W1n, W2p, W2n, xs, w16, n);
    gatherX_kernel<<<gridW, TPB, 0, stream>>>(rowse, edat, xs, dinvp, dinvn, agg, n);
    gemm12_mfma<<<gridF, TPB, 0, stream>>>(agg, w1p16, w1n16, b1p, b1n,
                                           w2p16, w2n16, dinvp, dinvn, g2, n);
    gather64_kernel<<<gridW, TPB, 0, stream>>>(rowse, edat, g2, dinvp, dinvn,
                                               b2p, b2n, out, n);
}